// Round 7
// baseline (3048.005 us; speedup 1.0000x reference)
//
#include <hip/hip_runtime.h>

#define LL 128      // memory length
#define BB 16       // batch
#define HH 512      // hidden
#define VV 16000    // vocab
#define TT 32       // steps
#define NH 8        // heads
#define DK 64       // head dim
#define NBLK 250    // mega grid (1 block/CU, co-resident)
#define NTHR 1024

// workspace layout (float offsets)
#define WS_K 0
#define WS_V (LL*BB*HH)                     // K,V: rows l*BB+b, 512 cols
#define WS_CTXT (2*LL*BB*HH)                // ctx transposed [k][b] (512*16)
#define WS_HS0 (WS_CTXT + BB*HH)            // h ping [k][b]
#define WS_HS1 (WS_HS0 + BB*HH)             // h pong [k][b]
#define WS_P   (WS_HS1 + BB*HH)             // p[b][h][128]
#define WS_CAND (WS_P + BB*NH*LL)           // u64 cand[blk][b]: 250*16
#define WS_ARRIVE (WS_CAND + 2*NBLK*BB)     // u32 arrive[250]
#define WS_SENSE (WS_ARRIVE + 256)          // u32

#define OUT_HID_OFF ((size_t)TT*BB*VV)
#define OUT_SC_OFF  (OUT_HID_OFF + (size_t)TT*BB*HH)

// ---- coherent (L2-bypassing, agent-scope relaxed atomic) access helpers ----
__device__ __forceinline__ float ld_coh1(const float* p) {
    unsigned v = __hip_atomic_load((const unsigned*)p, __ATOMIC_RELAXED,
                                   __HIP_MEMORY_SCOPE_AGENT);
    return __uint_as_float(v);
}
__device__ __forceinline__ void st_coh1(float* p, float a) {
    __hip_atomic_store((unsigned*)p, __float_as_uint(a), __ATOMIC_RELAXED,
                       __HIP_MEMORY_SCOPE_AGENT);
}
__device__ __forceinline__ unsigned long long ld_coh8(const unsigned long long* p) {
    return __hip_atomic_load(p, __ATOMIC_RELAXED, __HIP_MEMORY_SCOPE_AGENT);
}
__device__ __forceinline__ void st_coh8(unsigned long long* p, unsigned long long v) {
    __hip_atomic_store(p, v, __ATOMIC_RELAXED, __HIP_MEMORY_SCOPE_AGENT);
}
__device__ __forceinline__ float2 ld_coh2(const float* p) {
    unsigned long long v = ld_coh8((const unsigned long long*)p);
    float2 r; r.x = __uint_as_float((unsigned)v);
    r.y = __uint_as_float((unsigned)(v >> 32));
    return r;
}
__device__ __forceinline__ float4 ld_coh4(const float* p) {
    float2 a = ld_coh2(p), b = ld_coh2(p + 2);
    float4 r; r.x = a.x; r.y = a.y; r.z = b.x; r.w = b.y;
    return r;
}
__device__ __forceinline__ unsigned long long u64max(unsigned long long a,
                                                     unsigned long long b) {
    return a > b ? a : b;
}

// ---------------- kv projection + per-call init ----------------
__global__ __launch_bounds__(256) void kv_kernel(const float* __restrict__ mem,
        const float* __restrict__ Wk, const float* __restrict__ bk,
        const float* __restrict__ Wv, const float* __restrict__ bv,
        float* __restrict__ ws) {
    int blk = blockIdx.x;
    int rg = blk >> 4, ct = blk & 15;
    int isV = ct >= 8;
    int colbase = (ct & 7) * 64;
    const float* W = isV ? Wv : Wk;
    const float* bias = isV ? bv : bk;
    float* outp = ws + (isV ? WS_V : WS_K);
    int rowbase = rg * 16;
    int tid = threadIdx.x;
    __shared__ float As[16*516];

    {   // stage 16x512 A rows into padded LDS
        const float4* srcp = (const float4*)(mem + (size_t)rowbase*512);
        #pragma unroll
        for (int j = 0; j < 8; ++j) {
            int i = tid + 256*j;
            float4 v = srcp[i];
            int row = i >> 7, c4i = i & 127;
            *(float4*)(As + row*516 + c4i*4) = v;
        }
    }
    if (blk == 0) {
        for (int i = tid; i < BB*HH; i += 256) ws[WS_HS0 + i] = 0.f;   // h(-1)=0
    }
    __syncthreads();

    int cq = tid & 15;
    int rq4 = (tid >> 4) & 3;
    int kq = tid >> 6;
    float acc[4][4];
    #pragma unroll
    for (int i = 0; i < 4; ++i) { acc[i][0]=0.f; acc[i][1]=0.f; acc[i][2]=0.f; acc[i][3]=0.f; }
    const float* wp = W + colbase + cq*4;
    for (int k4 = kq*32; k4 < kq*32 + 32; ++k4) {
        float4 a0 = *(const float4*)(As + (rq4*4+0)*516 + k4*4);
        float4 a1 = *(const float4*)(As + (rq4*4+1)*516 + k4*4);
        float4 a2 = *(const float4*)(As + (rq4*4+2)*516 + k4*4);
        float4 a3 = *(const float4*)(As + (rq4*4+3)*516 + k4*4);
        const float* wrow = wp + (size_t)(4*k4)*512;
        float4 w0 = *(const float4*)(wrow);
        float4 w1 = *(const float4*)(wrow + 512);
        float4 w2 = *(const float4*)(wrow + 1024);
        float4 w3 = *(const float4*)(wrow + 1536);
        #define KV_FMA(ri, A) \
            acc[ri][0] += A.x*w0.x + A.y*w1.x + A.z*w2.x + A.w*w3.x; \
            acc[ri][1] += A.x*w0.y + A.y*w1.y + A.z*w2.y + A.w*w3.y; \
            acc[ri][2] += A.x*w0.z + A.y*w1.z + A.z*w2.z + A.w*w3.z; \
            acc[ri][3] += A.x*w0.w + A.y*w1.w + A.z*w2.w + A.w*w3.w;
        KV_FMA(0, a0) KV_FMA(1, a1) KV_FMA(2, a2) KV_FMA(3, a3)
        #undef KV_FMA
    }
    __syncthreads();
    float* red = As;
    #pragma unroll
    for (int ri = 0; ri < 4; ++ri)
        *(float4*)(red + ri*1024 + tid*4) =
            make_float4(acc[ri][0], acc[ri][1], acc[ri][2], acc[ri][3]);
    __syncthreads();
    {
        int c4 = tid & 15, row = tid >> 4;
        int rq = row >> 2, ri = row & 3;
        float4 b4v = *(const float4*)(bias + colbase + c4*4);
        float o[4] = {b4v.x, b4v.y, b4v.z, b4v.w};
        #pragma unroll
        for (int kq2 = 0; kq2 < 4; ++kq2) {
            const float* pr = red + ri*1024 + (kq2*64 + rq*16 + c4)*4;
            o[0] += pr[0]; o[1] += pr[1]; o[2] += pr[2]; o[3] += pr[3];
        }
        *(float4*)(outp + (size_t)(rowbase + row)*512 + colbase + c4*4) =
            make_float4(o[0], o[1], o[2], o[3]);
    }
}

// ---------------- grid barrier: store-arrive + scan (no RMW contention) ----
__device__ __forceinline__ void gridbar(float* ws, unsigned target) {
    unsigned* arrive = (unsigned*)(ws + WS_ARRIVE);
    unsigned* sense  = (unsigned*)(ws + WS_SENSE);
    __syncthreads();   // drains all waves' vmem (coherent stores complete)
    if (threadIdx.x == 0)
        __hip_atomic_store(&arrive[blockIdx.x], target, __ATOMIC_RELAXED,
                           __HIP_MEMORY_SCOPE_AGENT);
    if (blockIdx.x == 0 && threadIdx.x < 64) {
        for (;;) {
            bool ok = true;
            for (int j = threadIdx.x; j < NBLK; j += 64) {
                unsigned a = __hip_atomic_load(&arrive[j], __ATOMIC_RELAXED,
                                               __HIP_MEMORY_SCOPE_AGENT);
                if ((int)(a - target) < 0) ok = false;
            }
            if (__all(ok)) break;
            __builtin_amdgcn_s_sleep(1);
        }
        if (threadIdx.x == 0)
            __hip_atomic_store(sense, target, __ATOMIC_RELAXED,
                               __HIP_MEMORY_SCOPE_AGENT);
    }
    if (threadIdx.x == 0) {
        while ((int)(__hip_atomic_load(sense, __ATOMIC_RELAXED,
                     __HIP_MEMORY_SCOPE_AGENT) - target) < 0)
            __builtin_amdgcn_s_sleep(1);
    }
    __syncthreads();
}

// ---------------- mega kernel: all 32 steps ----------------
__global__ __launch_bounds__(NTHR) void mega_kernel(
        const float* __restrict__ emb, const float* __restrict__ Wq,
        const float* __restrict__ bq,
        const float* __restrict__ Wih, const float* __restrict__ bih,
        const float* __restrict__ Whh, const float* __restrict__ bhh,
        const float* __restrict__ Wf,  const float* __restrict__ bf,
        const int* __restrict__ olen, float* __restrict__ ws,
        float* __restrict__ out) {
    __shared__ float wf_s[3*512*16];                  // 96 KB: Wf cols [0..48) of this block
    __shared__ float hs_s[512*16];                    // 32 KB: h staging [k][b]
    __shared__ __align__(16) char scr[16384];         // 16 KB phase scratch
    int blk = blockIdx.x, tid = threadIdx.x;
    int colbase = blk * 64;
    unsigned long long* cand = (unsigned long long*)(ws + WS_CAND);
    unsigned s0;
    s0 = __hip_atomic_load((unsigned*)(ws + WS_SENSE), __ATOMIC_RELAXED,
                           __HIP_MEMORY_SCOPE_AGENT);
    unsigned bno = 0;

    {   // one-time: stage Wf cols [colbase, colbase+48) into LDS as [p][k][16]
        #pragma unroll
        for (int j = 0; j < 6; ++j) {
            int i = tid + NTHR*j;              // 6144 float4s: p = i/2048, k = (i%2048)>>2, c4 = i&3
            int p = i >> 11, rem = i & 2047;
            int k = rem >> 2, c4 = rem & 3;
            float4 v = *(const float4*)(Wf + (size_t)k*VV + colbase + p*16 + c4*4);
            *(float4*)(wf_s + ((p*512 + k)*16) + c4*4) = v;
        }
    }

    for (int t = 0; t < TT; ++t) {
        const float* hs_prev = ws + ((t & 1) ? WS_HS1 : WS_HS0);
        float* hs_new = ws + ((t & 1) ? WS_HS0 : WS_HS1);

        // ================= P1: attention (blocks 0..127) =================
        if (blk < 128) {
            int b = blk >> 3, h = blk & 7;
            float* q    = (float*)scr;                 // 1024 f @0
            float* part = q + 1024;                    // 16*64 f @4KB (qproj) / sp / cpart alias
            float* qh   = part + 2048;                 // 64 f @12KB
            float* pbuf = qh + 64;                     // 128 f

            unsigned idx = 0;
            if (t > 0) {   // resolve argmax from 250 block candidates (all waves redundant)
                unsigned long long m = 0ull;
                int l0 = tid & 63;
                for (int j = l0; j < NBLK; j += 64)
                    m = u64max(m, ld_coh8(&cand[j*BB + b]));
                #pragma unroll
                for (int off = 32; off; off >>= 1)
                    m = u64max(m, (unsigned long long)__shfl_xor((long long)m, off));
                idx = 0xFFFFFFFFu - (unsigned)(m & 0xFFFFFFFFull);
            }
            if (tid < 512) q[tid] = emb[(size_t)idx*HH + tid];
            else { int j = tid - 512; q[512 + j] = ld_coh1(hs_prev + j*16 + b); }
            __syncthreads();

            {   // qproj: c4 = tid&15 (4 cols of 64), kc = tid>>4 (64 k-slices), k = kc+64i, i<16
                int c4 = tid & 15, kc = tid >> 4;
                const float* wp = Wq + (size_t)kc*HH + h*64 + c4*4;
                float ax=0.f, ay=0.f, az=0.f, aw=0.f;
                #pragma unroll
                for (int i = 0; i < 16; ++i) {
                    float x = q[kc + 64*i];
                    float4 w4 = *(const float4*)wp;
                    wp += (size_t)64*HH;
                    ax += x*w4.x; ay += x*w4.y; az += x*w4.z; aw += x*w4.w;
                }
                float v;
                v = ax; v += __shfl_xor(v,16); v += __shfl_xor(v,32); ax = v;
                v = ay; v += __shfl_xor(v,16); v += __shfl_xor(v,32); ay = v;
                v = az; v += __shfl_xor(v,16); v += __shfl_xor(v,32); az = v;
                v = aw; v += __shfl_xor(v,16); v += __shfl_xor(v,32); aw = v;
                int wv = tid >> 6;
                if ((tid & 48) == 0)
                    *(float4*)(part + wv*64 + c4*4) = make_float4(ax, ay, az, aw);
            }
            __syncthreads();
            if (tid < 64) {
                float s = bq[h*64 + tid];
                #pragma unroll
                for (int wv = 0; wv < 16; ++wv) s += part[wv*64 + tid];
                qh[tid] = s;
            }
            __syncthreads();

            float* sp = part;   // 8*128 f
            {   // scores: l = tid&127, jh = tid>>7 (8 slices of 8 k)
                int l = tid & 127, jh = tid >> 7;
                const float4* kr = (const float4*)(ws + WS_K +
                                   ((size_t)(l*BB + b))*HH + h*DK) + jh*2;
                const float4* q4 = (const float4*)qh + jh*2;
                float4 k0 = kr[0], k1 = kr[1], q0 = q4[0], q1 = q4[1];
                sp[jh*128 + l] = q0.x*k0.x + q0.y*k0.y + q0.z*k0.z + q0.w*k0.w
                               + q1.x*k1.x + q1.y*k1.y + q1.z*k1.z + q1.w*k1.w;
            }
            __syncthreads();

            if (tid < 64) {   // softmax over 128 (wave 0)
                float s0v = 0.f, s1v = 0.f;
                #pragma unroll
                for (int jh = 0; jh < 8; ++jh) {
                    s0v += sp[jh*128 + tid];
                    s1v += sp[jh*128 + 64 + tid];
                }
                s0v *= 0.125f; s1v *= 0.125f;
                float m = fmaxf(s0v, s1v);
                #pragma unroll
                for (int off = 32; off; off >>= 1) m = fmaxf(m, __shfl_xor(m, off));
                float e0 = __expf(s0v - m), e1 = __expf(s1v - m);
                float sum = e0 + e1;
                #pragma unroll
                for (int off = 32; off; off >>= 1) sum += __shfl_xor(sum, off);
                float inv = 1.f / sum;
                pbuf[tid]      = e0 * inv;
                pbuf[64 + tid] = e1 * inv;
            }
            __syncthreads();
            if (tid < 128)
                st_coh1(ws + WS_P + (size_t)(b*NH + h)*LL + tid, pbuf[tid]);

            float* cpart = part;   // 16*64 f (sp reads finished)
            {   // ctx: c = tid&63, lc = tid>>6 (16 slices of 8 l)
                int c = tid & 63, lc = tid >> 6;
                const float* Vp = ws + WS_V + h*DK + c;
                float a = 0.f;
                #pragma unroll
                for (int li = 0; li < 8; ++li) {
                    int l = lc*8 + li;
                    a += pbuf[l] * Vp[(size_t)(l*BB + b)*HH];
                }
                cpart[lc*64 + c] = a;
            }
            __syncthreads();
            if (tid < 64) {
                float v = 0.f;
                #pragma unroll
                for (int lc = 0; lc < 16; ++lc) v += cpart[lc*64 + tid];
                st_coh1(ws + WS_CTXT + (size_t)(h*64 + tid)*16 + b, v);
            }
        }
        ++bno; gridbar(ws, s0 + bno);

        // ================= P2: GRU gates + finalize (blocks 0..31) =======
        if (blk < 32) {
            int cb = blk;
            float* part = (float*)scr;                 // 16*256 f = 16 KB

            if (tid < 64) {   // sc output: 64 of 2048 (b,l) per block
                int e = cb*64 + tid;
                int b = e >> 7, l = e & 127;
                float s = 0.f;
                #pragma unroll
                for (int hq = 0; hq < NH; ++hq)
                    s += ld_coh1(ws + WS_P + (size_t)(b*NH + hq)*LL + l);
                float v = (t < olen[b]) ? s*0.125f : 0.f;
                __builtin_nontemporal_store(v,
                    out + OUT_SC_OFF + ((size_t)t*BB + b)*LL + l);
            }

            int c4 = tid & 3, b4 = (tid >> 2) & 3, kc = tid >> 4;  // kc 0..63
            int wv = tid >> 6;
            float4 xv[8];
            #pragma unroll
            for (int i = 0; i < 8; ++i)
                xv[i] = ld_coh4(ws + WS_CTXT + (size_t)(kc + 64*i)*16 + b4*4);
            float vg[6];

            #pragma unroll
            for (int g = 0; g < 6; ++g) {
                if (g == 3) {
                    #pragma unroll
                    for (int i = 0; i < 8; ++i)
                        xv[i] = ld_coh4(hs_prev + (size_t)(kc + 64*i)*16 + b4*4);
                }
                const float* W = (g < 3) ? Wih : Whh;
                int gg = (g < 3) ? g : g - 3;
                const float* wp = W + (size_t)kc*(3*HH) + gg*HH + cb*16 + c4*4;
                float acc[4][4];
                #pragma unroll
                for (int i = 0; i < 4; ++i) { acc[i][0]=0.f; acc[i][1]=0.f; acc[i][2]=0.f; acc[i][3]=0.f; }
                #pragma unroll
                for (int i = 0; i < 8; ++i) {     // k = kc + 64*i
                    float4 w4 = *(const float4*)wp;
                    wp += (size_t)64*(3*HH);
                    float4 x4 = xv[i];
                    acc[0][0] += x4.x*w4.x; acc[0][1] += x4.x*w4.y; acc[0][2] += x4.x*w4.z; acc[0][3] += x4.x*w4.w;
                    acc[1][0] += x4.y*w4.x; acc[1][1] += x4.y*w4.y; acc[1][2] += x4.y*w4.z; acc[1][3] += x4.y*w4.w;
                    acc[2][0] += x4.z*w4.x; acc[2][1] += x4.z*w4.y; acc[2][2] += x4.z*w4.z; acc[2][3] += x4.z*w4.w;
                    acc[3][0] += x4.w*w4.x; acc[3][1] += x4.w*w4.y; acc[3][2] += x4.w*w4.z; acc[3][3] += x4.w*w4.w;
                }
                #pragma unroll
                for (int bi = 0; bi < 4; ++bi)
                    #pragma unroll
                    for (int ci = 0; ci < 4; ++ci) {
                        float v = acc[bi][ci];
                        v += __shfl_xor(v, 16);
                        v += __shfl_xor(v, 32);
                        acc[bi][ci] = v;
                    }
                if ((tid & 48) == 0) {
                    #pragma unroll
                    for (int bi = 0; bi < 4; ++bi)
                        *(float4*)(part + wv*256 + (b4*4+bi)*16 + c4*4) =
                            make_float4(acc[bi][0], acc[bi][1], acc[bi][2], acc[bi][3]);
                }
                __syncthreads();
                float s = 0.f;
                if (tid < 256) {
                    #pragma unroll
                    for (int w = 0; w < 16; ++w) s += part[w*256 + tid];
                }
                vg[g] = s;
                __syncthreads();
            }

            if (tid < 256) {   // finalize
                int b = tid >> 4, c = tid & 15;
                int col = cb*16 + c;
                float gir = vg[0] + bih[col];
                float giz = vg[1] + bih[HH + col];
                float gin = vg[2] + bih[2*HH + col];
                float ghr = vg[3] + bhh[col];
                float ghz = vg[4] + bhh[HH + col];
                float ghn = vg[5] + bhh[2*HH + col];
                float r = 1.f/(1.f + __expf(-(gir + ghr)));
                float z = 1.f/(1.f + __expf(-(giz + ghz)));
                float xn = gin + r*ghn;
                float n = 1.f - 2.f/(__expf(2.f*xn) + 1.f);
                float hprev = ld_coh1(hs_prev + col*16 + b);
                float hnew = (1.f - z)*n + z*hprev;
                st_coh1(hs_new + col*16 + b, hnew);
                float hv = (t < olen[b]) ? hnew : 0.f;
                __builtin_nontemporal_store(hv,
                    out + OUT_HID_OFF + ((size_t)t*BB + b)*HH + col);
            }
        }
        ++bno; gridbar(ws, s0 + bno);

        // ================= P3: logits + per-block argmax (all 250) =======
        {
            float* part = (float*)scr;     // 16*256 f = 16 KB
            {   // stage h_new [k][b] -> hs_s (coherent)
                #pragma unroll
                for (int j = 0; j < 2; ++j) {
                    int i = tid + NTHR*j;                  // 2048 float4s
                    float4 v = ld_coh4(hs_new + (size_t)i*4);
                    *(float4*)(hs_s + i*4) = v;
                }
            }
            __syncthreads();

            int c4 = tid & 3, bq = (tid >> 2) & 3, kc = tid >> 4;  // kc 0..63
            int wv = tid >> 6;
            unsigned long long vmax = 0ull;

            #pragma unroll
            for (int p = 0; p < 4; ++p) {   // passes: 0-2 LDS cols, 3 global cols
                float acc[4][4];
                #pragma unroll
                for (int i = 0; i < 4; ++i) { acc[i][0]=0.f; acc[i][1]=0.f; acc[i][2]=0.f; acc[i][3]=0.f; }
                #pragma unroll
                for (int i = 0; i < 8; ++i) {   // k = kc + 64*i
                    int k = kc + 64*i;
                    float4 w4;
                    if (p < 3) w4 = *(const float4*)(wf_s + ((p*512 + k)*16) + c4*4);
                    else       w4 = *(const float4*)(Wf + (size_t)k*VV + colbase + 48 + c4*4);
                    float4 h4 = *(const float4*)(hs_s + k*16 + bq*4);
                    acc[0][0] += h4.x*w4.x; acc[0][1] += h4.x*w4.y; acc[0][2] += h4.x*w4.z; acc[0][3] += h4.x*w4.w;
                    acc[1][0] += h4.y*w4.x; acc[1][1] += h4.y*w4.y; acc[1][2] += h4.y*w4.z; acc[1][3] += h4.y*w4.w;
                    acc[2][0] += h4.z*w4.x; acc[2][1] += h4.z*w4.y; acc[2][2] += h4.z*w4.z; acc[2][3] += h4.z*w4.w;
                    acc[3][0] += h4.w*w4.x; acc[3][1] += h4.w*w4.y; acc[3][2] += h4.w*w4.z; acc[3][3] += h4.w*w4.w;
                }
                #pragma unroll
                for (int bi = 0; bi < 4; ++bi)
                    #pragma unroll
                    for (int ci = 0; ci < 4; ++ci) {
                        float v = acc[bi][ci];
                        v += __shfl_xor(v, 16);
                        v += __shfl_xor(v, 32);
                        acc[bi][ci] = v;
                    }
                if ((tid & 48) == 0) {
                    #pragma unroll
                    for (int bi = 0; bi < 4; ++bi)
                        *(float4*)(part + wv*256 + (bq*4+bi)*16 + c4*4) =
                            make_float4(acc[bi][0], acc[bi][1], acc[bi][2], acc[bi][3]);
                }
                __syncthreads();
                if (tid < 256) {
                    int b = tid >> 4, c = tid & 15;
                    int col = colbase + p*16 + c;
                    float s = bf[col];
                    #pragma unroll
                    for (int w = 0; w < 16; ++w) s += part[w*256 + tid];
                    bool active = t < olen[b];
                    __builtin_nontemporal_store(active ? s : 0.f,
                        out + ((size_t)t*BB + b)*VV + col);
                    unsigned u = __float_as_uint(s);
                    u = (u & 0x80000000u) ? ~u : (u | 0x80000000u);
                    unsigned long long e = ((unsigned long long)u << 32)
                        | (unsigned long long)(0xFFFFFFFFu - (unsigned)col);
                    #pragma unroll
                    for (int off = 1; off < 16; off <<= 1)
                        e = u64max(e, (unsigned long long)__shfl_xor((long long)e, off));
                    if ((tid & 15) == 0) vmax = u64max(vmax, e);
                }
                __syncthreads();
            }
            if (tid < 256 && (tid & 15) == 0)
                st_coh8(&cand[blk*BB + (tid >> 4)], vmax);
        }
        if (t < TT - 1) { ++bno; gridbar(ws, s0 + bno); }
    }
}

extern "C" void kernel_launch(void* const* d_in, const int* in_sizes, int n_in,
                              void* d_out, int out_size, void* d_ws, size_t ws_size,
                              hipStream_t stream) {
    const float* mem = (const float*)d_in[0];
    const float* emb = (const float*)d_in[1];
    const float* Wq  = (const float*)d_in[2];
    const float* bq  = (const float*)d_in[3];
    const float* Wk  = (const float*)d_in[4];
    const float* bk  = (const float*)d_in[5];
    const float* Wv  = (const float*)d_in[6];
    const float* bv  = (const float*)d_in[7];
    const float* Wih = (const float*)d_in[8];
    const float* bih = (const float*)d_in[9];
    const float* Whh = (const float*)d_in[10];
    const float* bhh = (const float*)d_in[11];
    const float* Wf  = (const float*)d_in[12];
    const float* bf  = (const float*)d_in[13];
    const int* olen  = (const int*)d_in[14];
    float* out = (float*)d_out;
    float* ws  = (float*)d_ws;

    hipLaunchKernelGGL(kv_kernel, dim3(2048), dim3(256), 0, stream, mem, Wk, bk, Wv, bv, ws);
    hipLaunchKernelGGL(mega_kernel, dim3(NBLK), dim3(NTHR), 0, stream,
                       emb, Wq, bq, Wih, bih, Whh, bhh, Wf, bf, olen, ws, out);
}

// Round 9
// 2750.486 us; speedup vs baseline: 1.1082x; 1.1082x over previous
//
#include <hip/hip_runtime.h>

#define LL 128      // memory length
#define BB 16       // batch
#define HH 512      // hidden
#define VV 16000    // vocab
#define TT 32       // steps
#define NH 8        // heads
#define DK 64       // head dim
#define NBLK 250    // mega grid (1 block/CU, co-resident)
#define NTHR 1024

// workspace layout (float offsets)
#define WS_K 0
#define WS_V (LL*BB*HH)                 // K,V: rows l*BB+b, 512 cols (cached, RO)
#define WS_CTXB (2*LL*BB*HH)            // ctx [b][k]           (sc-only region)
#define WS_HS0 (WS_CTXB + BB*HH)        // h [k][b] ping        (sc-only)
#define WS_HS1 (WS_HS0 + BB*HH)         // h [k][b] pong
#define WS_HBK0 (WS_HS1 + BB*HH)        // h [b][k] ping
#define WS_HBK1 (WS_HBK0 + BB*HH)       // h [b][k] pong
#define WS_P (WS_HBK1 + BB*HH)          // p[b][h][128]         (sc-only)
#define WS_CAND (WS_P + BB*NH*LL)       // u64 cand[256][16]    (sc-only)
#define WS_CNT (WS_CAND + 2*256*BB)
#define WS_SENSE (WS_CNT + 32)

#define OUT_HID_OFF ((size_t)TT*BB*VV)
#define OUT_SC_OFF  (OUT_HID_OFF + (size_t)TT*BB*HH)

typedef float v4f __attribute__((ext_vector_type(4)));
typedef unsigned long long u64;

__device__ __forceinline__ u64 u64max(u64 a, u64 b) { return a > b ? a : b; }

// ---- 16B cache-bypassing (sc0+sc1 -> coherent at LLC) load/store helpers ----
__device__ __forceinline__ float4 ldnc4(const float* p) {
    v4f r;
    asm volatile("global_load_dwordx4 %0, %1, off sc0 sc1\n\t"
                 "s_waitcnt vmcnt(0)"
                 : "=&v"(r) : "v"(p) : "memory");
    return make_float4(r.x, r.y, r.z, r.w);
}
__device__ __forceinline__ void ldnc4x2(const float* p0, const float* p1,
                                        float4& a, float4& b) {
    v4f ra, rb;
    asm volatile("global_load_dwordx4 %0, %2, off sc0 sc1\n\t"
                 "global_load_dwordx4 %1, %3, off sc0 sc1\n\t"
                 "s_waitcnt vmcnt(0)"
                 : "=&v"(ra), "=&v"(rb) : "v"(p0), "v"(p1) : "memory");
    a = make_float4(ra.x, ra.y, ra.z, ra.w);
    b = make_float4(rb.x, rb.y, rb.z, rb.w);
}
__device__ __forceinline__ void ldnc8x4(const u64* p0, const u64* p1,
        const u64* p2, const u64* p3, u64& a, u64& b, u64& c, u64& d) {
    asm volatile("global_load_dwordx2 %0, %4, off sc0 sc1\n\t"
                 "global_load_dwordx2 %1, %5, off sc0 sc1\n\t"
                 "global_load_dwordx2 %2, %6, off sc0 sc1\n\t"
                 "global_load_dwordx2 %3, %7, off sc0 sc1\n\t"
                 "s_waitcnt vmcnt(0)"
                 : "=&v"(a), "=&v"(b), "=&v"(c), "=&v"(d)
                 : "v"(p0), "v"(p1), "v"(p2), "v"(p3) : "memory");
}
__device__ __forceinline__ void stnc4(float* p, float4 v) {
    v4f r; r.x = v.x; r.y = v.y; r.z = v.z; r.w = v.w;
    asm volatile("global_store_dwordx4 %0, %1, off sc0 sc1"
                 :: "v"(p), "v"(r) : "memory");
}
__device__ __forceinline__ void stnc1(float* p, float v) {
    asm volatile("global_store_dword %0, %1, off sc0 sc1"
                 :: "v"(p), "v"(v) : "memory");
}

// ---------------- kv projection + per-call init ----------------
__global__ __launch_bounds__(256) void kv_kernel(const float* __restrict__ mem,
        const float* __restrict__ Wk, const float* __restrict__ bk,
        const float* __restrict__ Wv, const float* __restrict__ bv,
        float* __restrict__ ws) {
    int blk = blockIdx.x;
    int rg = blk >> 4, ct = blk & 15;
    int isV = ct >= 8;
    int colbase = (ct & 7) * 64;
    const float* W = isV ? Wv : Wk;
    const float* bias = isV ? bv : bk;
    float* outp = ws + (isV ? WS_V : WS_K);
    int rowbase = rg * 16;
    int tid = threadIdx.x;
    __shared__ float As[16*516];

    {
        const float4* srcp = (const float4*)(mem + (size_t)rowbase*512);
        #pragma unroll
        for (int j = 0; j < 8; ++j) {
            int i = tid + 256*j;
            float4 v = srcp[i];
            int row = i >> 7, c4i = i & 127;
            *(float4*)(As + row*516 + c4i*4) = v;
        }
    }
    if (blk == 0) {   // per-call init (normal stores; kernel-end writeback -> LLC)
        for (int i = tid; i < BB*HH; i += 256) {
            ws[WS_HS0 + i] = 0.f;
            ws[WS_HBK0 + i] = 0.f;
        }
        u64* cand = (u64*)(ws + WS_CAND);
        for (int i = tid; i < 256*BB; i += 256) cand[i] = 0ull;
        if (tid == 0) {
            *(unsigned*)(ws + WS_CNT) = 0u;
            *(unsigned*)(ws + WS_SENSE) = 0u;
        }
    }
    __syncthreads();

    int cq = tid & 15;
    int rq4 = (tid >> 4) & 3;
    int kq = tid >> 6;
    float acc[4][4];
    #pragma unroll
    for (int i = 0; i < 4; ++i) { acc[i][0]=0.f; acc[i][1]=0.f; acc[i][2]=0.f; acc[i][3]=0.f; }
    const float* wp = W + colbase + cq*4;
    for (int k4 = kq*32; k4 < kq*32 + 32; ++k4) {
        float4 a0 = *(const float4*)(As + (rq4*4+0)*516 + k4*4);
        float4 a1 = *(const float4*)(As + (rq4*4+1)*516 + k4*4);
        float4 a2 = *(const float4*)(As + (rq4*4+2)*516 + k4*4);
        float4 a3 = *(const float4*)(As + (rq4*4+3)*516 + k4*4);
        const float* wrow = wp + (size_t)(4*k4)*512;
        float4 w0 = *(const float4*)(wrow);
        float4 w1 = *(const float4*)(wrow + 512);
        float4 w2 = *(const float4*)(wrow + 1024);
        float4 w3 = *(const float4*)(wrow + 1536);
        #define KV_FMA(ri, A) \
            acc[ri][0] += A.x*w0.x + A.y*w1.x + A.z*w2.x + A.w*w3.x; \
            acc[ri][1] += A.x*w0.y + A.y*w1.y + A.z*w2.y + A.w*w3.y; \
            acc[ri][2] += A.x*w0.z + A.y*w1.z + A.z*w2.z + A.w*w3.z; \
            acc[ri][3] += A.x*w0.w + A.y*w1.w + A.z*w2.w + A.w*w3.w;
        KV_FMA(0, a0) KV_FMA(1, a1) KV_FMA(2, a2) KV_FMA(3, a3)
        #undef KV_FMA
    }
    __syncthreads();
    float* red = As;
    #pragma unroll
    for (int ri = 0; ri < 4; ++ri)
        *(float4*)(red + ri*1024 + tid*4) =
            make_float4(acc[ri][0], acc[ri][1], acc[ri][2], acc[ri][3]);
    __syncthreads();
    {
        int c4 = tid & 15, row = tid >> 4;
        int rq = row >> 2, ri = row & 3;
        float4 b4v = *(const float4*)(bias + colbase + c4*4);
        float o[4] = {b4v.x, b4v.y, b4v.z, b4v.w};
        #pragma unroll
        for (int kq2 = 0; kq2 < 4; ++kq2) {
            const float* pr = red + ri*1024 + (kq2*64 + rq*16 + c4)*4;
            o[0] += pr[0]; o[1] += pr[1]; o[2] += pr[2]; o[3] += pr[3];
        }
        *(float4*)(outp + (size_t)(rowbase + row)*512 + colbase + c4*4) =
            make_float4(o[0], o[1], o[2], o[3]);
    }
}

// ------------- grid barrier (fetch-add + sense; kv resets per call) ---------
__device__ __forceinline__ void gridbar(float* ws, unsigned target) {
    unsigned* cnt = (unsigned*)(ws + WS_CNT);
    unsigned* sense = (unsigned*)(ws + WS_SENSE);
    asm volatile("s_waitcnt vmcnt(0)" ::: "memory");   // drain this wave's sc stores
    __syncthreads();
    if (threadIdx.x == 0) {
        unsigned old = __hip_atomic_fetch_add(cnt, 1u, __ATOMIC_RELAXED,
                                              __HIP_MEMORY_SCOPE_AGENT);
        if (old == (unsigned)NBLK - 1u) {
            __hip_atomic_store(cnt, 0u, __ATOMIC_RELAXED, __HIP_MEMORY_SCOPE_AGENT);
            asm volatile("s_waitcnt vmcnt(0)" ::: "memory");
            __hip_atomic_store(sense, target, __ATOMIC_RELAXED, __HIP_MEMORY_SCOPE_AGENT);
        } else {
            while ((int)(__hip_atomic_load(sense, __ATOMIC_RELAXED,
                         __HIP_MEMORY_SCOPE_AGENT) - target) < 0)
                __builtin_amdgcn_s_sleep(4);
        }
    }
    __syncthreads();
}

// ---------------- mega kernel: all 32 steps ----------------
__global__ __launch_bounds__(NTHR) void mega_kernel(
        const float* __restrict__ emb, const float* __restrict__ Wq,
        const float* __restrict__ bq,
        const float* __restrict__ Wih, const float* __restrict__ bih,
        const float* __restrict__ Whh, const float* __restrict__ bhh,
        const float* __restrict__ Wf,  const float* __restrict__ bf,
        const int* __restrict__ olen, float* __restrict__ ws,
        float* __restrict__ out) {
    __shared__ float wf_s[3*512*16];              // 96 KB: Wf cols [blk*64, +48)
    __shared__ float hs_s[512*16];                // 32 KB: [k][16] staging
    __shared__ __align__(16) float scr[4096];     // 16 KB phase scratch
    int blk = blockIdx.x, tid = threadIdx.x;
    int colbase = blk * 64;
    u64* cand = (u64*)(ws + WS_CAND);
    unsigned bno = 0;

    {   // one-time: stage Wf cols [colbase, colbase+48) into LDS (cached reads)
        #pragma unroll
        for (int j = 0; j < 6; ++j) {
            int i = tid + NTHR*j;                 // 6144 float4
            int p = i >> 11, rem = i & 2047;
            int k = rem >> 2, c4 = rem & 3;
            float4 v = *(const float4*)(Wf + (size_t)k*VV + colbase + p*16 + c4*4);
            *(float4*)(wf_s + (p*512 + k)*16 + c4*4) = v;
        }
    }

    for (int t = 0; t < TT; ++t) {
        const float* hs_prev  = ws + ((t & 1) ? WS_HS1  : WS_HS0);
        float*       hs_new   = ws + ((t & 1) ? WS_HS0  : WS_HS1);
        const float* hbk_prev = ws + ((t & 1) ? WS_HBK1 : WS_HBK0);
        float*       hbk_new  = ws + ((t & 1) ? WS_HBK0 : WS_HBK1);

        // ================= P1: attention (blocks 0..127) =================
        if (blk < 128) {
            int b = blk >> 3, h = blk & 7;
            float* q    = scr;                    // 1024
            float* buf  = scr + 1024;             // 1024 (part / sp / cpart)
            float* qh   = scr + 2048;             // 64
            float* pbuf = scr + 2112;             // 128
            float* ctxv = scr + 2240;             // 64

            if (t > 0) {   // resolve argmax from 256 (padded) block candidates
                if (tid < 64) {
                    const u64* cp = cand + b;
                    u64 a0, a1, a2, a3;
                    ldnc8x4(cp + (size_t)tid*BB, cp + (size_t)(tid+64)*BB,
                            cp + (size_t)(tid+128)*BB, cp + (size_t)(tid+192)*BB,
                            a0, a1, a2, a3);
                    u64 m = u64max(u64max(a0, a1), u64max(a2, a3));
                    #pragma unroll
                    for (int off = 32; off; off >>= 1)
                        m = u64max(m, (u64)__shfl_xor((long long)m, off));
                    if (tid == 0)
                        *(unsigned*)(scr + 2304) = 0xFFFFFFFFu - (unsigned)(m & 0xFFFFFFFFull);
                }
                __syncthreads();
            }
            unsigned idx = (t > 0) ? *(unsigned*)(scr + 2304) : 0u;
            if (tid < 128) {
                *(float4*)(q + tid*4) = ((const float4*)emb)[(size_t)idx*128 + tid];
            } else if (tid < 256) {
                int j = tid - 128;
                *(float4*)(q + 512 + j*4) = ldnc4(hbk_prev + (size_t)b*HH + j*4);
            }
            __syncthreads();

            {   // qproj: c4 = tid&15 (4 cols), kc = tid>>4 (k = kc + 64i)
                int c4 = tid & 15, kc = tid >> 4;
                const float* wp = Wq + (size_t)kc*HH + h*64 + c4*4;
                float ax=0.f, ay=0.f, az=0.f, aw=0.f;
                #pragma unroll
                for (int i = 0; i < 16; ++i) {
                    float x = q[kc + 64*i];
                    float4 w4 = *(const float4*)wp;
                    wp += (size_t)64*HH;
                    ax += x*w4.x; ay += x*w4.y; az += x*w4.z; aw += x*w4.w;
                }
                float v;
                v = ax; v += __shfl_xor(v,16); v += __shfl_xor(v,32); ax = v;
                v = ay; v += __shfl_xor(v,16); v += __shfl_xor(v,32); ay = v;
                v = az; v += __shfl_xor(v,16); v += __shfl_xor(v,32); az = v;
                v = aw; v += __shfl_xor(v,16); v += __shfl_xor(v,32); aw = v;
                int wv = tid >> 6;
                if ((tid & 48) == 0)
                    *(float4*)(buf + wv*64 + c4*4) = make_float4(ax, ay, az, aw);
            }
            __syncthreads();
            if (tid < 64) {
                float s = bq[h*64 + tid];
                #pragma unroll
                for (int wv = 0; wv < 16; ++wv) s += buf[wv*64 + tid];
                qh[tid] = s;
            }
            __syncthreads();

            {   // scores: l = tid&127, jh = tid>>7 (8 slices of 8 k)
                int l = tid & 127, jh = tid >> 7;
                const float4* kr = (const float4*)(ws + WS_K +
                                   ((size_t)(l*BB + b))*HH + h*DK) + jh*2;
                const float4* q4 = (const float4*)qh + jh*2;
                float4 k0 = kr[0], k1 = kr[1], q0 = q4[0], q1 = q4[1];
                buf[jh*128 + l] = q0.x*k0.x + q0.y*k0.y + q0.z*k0.z + q0.w*k0.w
                                + q1.x*k1.x + q1.y*k1.y + q1.z*k1.z + q1.w*k1.w;
            }
            __syncthreads();

            if (tid < 64) {   // softmax over 128 (wave 0)
                float s0v = 0.f, s1v = 0.f;
                #pragma unroll
                for (int jh = 0; jh < 8; ++jh) {
                    s0v += buf[jh*128 + tid];
                    s1v += buf[jh*128 + 64 + tid];
                }
                s0v *= 0.125f; s1v *= 0.125f;
                float m = fmaxf(s0v, s1v);
                #pragma unroll
                for (int off = 32; off; off >>= 1) m = fmaxf(m, __shfl_xor(m, off));
                float e0 = __expf(s0v - m), e1 = __expf(s1v - m);
                float sum = e0 + e1;
                #pragma unroll
                for (int off = 32; off; off >>= 1) sum += __shfl_xor(sum, off);
                float inv = 1.f / sum;
                pbuf[tid]      = e0 * inv;
                pbuf[64 + tid] = e1 * inv;
            }
            __syncthreads();
            if (tid < 32)
                stnc4(ws + WS_P + (size_t)(b*NH + h)*LL + tid*4,
                      *(float4*)(pbuf + tid*4));

            {   // ctx: c = tid&63, lc = tid>>6 (16 slices of 8 l)
                int c = tid & 63, lc = tid >> 6;
                const float* Vp = ws + WS_V + h*DK + c;
                float a = 0.f;
                #pragma unroll
                for (int li = 0; li < 8; ++li) {
                    int l = lc*8 + li;
                    a += pbuf[l] * Vp[(size_t)(l*BB + b)*HH];
                }
                buf[lc*64 + c] = a;
            }
            __syncthreads();
            if (tid < 64) {
                float v = 0.f;
                #pragma unroll
                for (int lc = 0; lc < 16; ++lc) v += buf[lc*64 + tid];
                ctxv[tid] = v;
            }
            __syncthreads();
            if (tid < 16)
                stnc4(ws + WS_CTXB + (size_t)b*HH + h*64 + tid*4,
                      *(float4*)(ctxv + tid*4));
        }
        ++bno; gridbar(ws, bno);

        // ================= P2: GRU gates + finalize (blocks 0..31) =======
        if (blk < 32) {
            int cb = blk;
            int bb = cb >> 1, l0 = (cb & 1) * 64;

            if (tid < 128) {   // P slices for sc output -> scr[2048..2559]
                int hq = tid >> 4, li = (tid & 15) * 4;
                float4 pv = ldnc4(ws + WS_P + (size_t)(bb*NH + hq)*LL + l0 + li);
                *(float4*)(scr + 2048 + hq*64 + li) = pv;
            }
            {   // ctx [b][k] -> hs_s [k][16]
                int b = tid & 15, kq = tid >> 4;     // k = kq*8 .. +7
                float4 v0, v1;
                ldnc4x2(ws + WS_CTXB + (size_t)b*HH + kq*8,
                        ws + WS_CTXB + (size_t)b*HH + kq*8 + 4, v0, v1);
                hs_s[(kq*8+0)*16 + b] = v0.x; hs_s[(kq*8+1)*16 + b] = v0.y;
                hs_s[(kq*8+2)*16 + b] = v0.z; hs_s[(kq*8+3)*16 + b] = v0.w;
                hs_s[(kq*8+4)*16 + b] = v1.x; hs_s[(kq*8+5)*16 + b] = v1.y;
                hs_s[(kq*8+6)*16 + b] = v1.z; hs_s[(kq*8+7)*16 + b] = v1.w;
            }
            __syncthreads();
            if (tid < 64) {   // sc output
                float s = 0.f;
                #pragma unroll
                for (int hq = 0; hq < NH; ++hq) s += scr[2048 + hq*64 + tid];
                float v = (t < olen[bb]) ? s*0.125f : 0.f;
                __builtin_nontemporal_store(v,
                    out + OUT_SC_OFF + ((size_t)t*BB + bb)*LL + l0 + tid);
            }
            __syncthreads();

            int c4 = tid & 3, b4 = (tid >> 2) & 3, kc = tid >> 4;
            int wv = tid >> 6;
            float4 xv[8];
            #pragma unroll
            for (int i = 0; i < 8; ++i)
                xv[i] = *(const float4*)(hs_s + (kc + 64*i)*16 + b4*4);
            float vg[6];

            #define GATE(gslot, WMAT, GG) { \
                const float* wp = WMAT + (size_t)kc*(3*HH) + (GG)*HH + cb*16 + c4*4; \
                float a00=0,a01=0,a02=0,a03=0, a10=0,a11=0,a12=0,a13=0; \
                float a20=0,a21=0,a22=0,a23=0, a30=0,a31=0,a32=0,a33=0; \
                _Pragma("unroll") \
                for (int i = 0; i < 8; ++i) { \
                    float4 w4 = *(const float4*)wp; wp += (size_t)64*(3*HH); \
                    float4 x4 = xv[i]; \
                    a00 += x4.x*w4.x; a01 += x4.x*w4.y; a02 += x4.x*w4.z; a03 += x4.x*w4.w; \
                    a10 += x4.y*w4.x; a11 += x4.y*w4.y; a12 += x4.y*w4.z; a13 += x4.y*w4.w; \
                    a20 += x4.z*w4.x; a21 += x4.z*w4.y; a22 += x4.z*w4.z; a23 += x4.z*w4.w; \
                    a30 += x4.w*w4.x; a31 += x4.w*w4.y; a32 += x4.w*w4.z; a33 += x4.w*w4.w; \
                } \
                float acc2[4][4] = {{a00,a01,a02,a03},{a10,a11,a12,a13}, \
                                    {a20,a21,a22,a23},{a30,a31,a32,a33}}; \
                _Pragma("unroll") \
                for (int bi = 0; bi < 4; ++bi) \
                    _Pragma("unroll") \
                    for (int ci = 0; ci < 4; ++ci) { \
                        float vz = acc2[bi][ci]; \
                        vz += __shfl_xor(vz, 16); \
                        vz += __shfl_xor(vz, 32); \
                        acc2[bi][ci] = vz; \
                    } \
                if ((tid & 48) == 0) { \
                    _Pragma("unroll") \
                    for (int bi = 0; bi < 4; ++bi) \
                        *(float4*)(scr + wv*256 + (b4*4+bi)*16 + c4*4) = \
                            make_float4(acc2[bi][0], acc2[bi][1], acc2[bi][2], acc2[bi][3]); \
                } \
                __syncthreads(); \
                float sred = 0.f; \
                if (tid < 256) { \
                    _Pragma("unroll") \
                    for (int w = 0; w < 16; ++w) sred += scr[w*256 + tid]; \
                } \
                vg[gslot] = sred; \
                __syncthreads(); }

            GATE(0, Wih, 0) GATE(1, Wih, 1) GATE(2, Wih, 2)

            {   // restage hs_s with h_prev [k][b] (direct copy)
                float4 v0, v1;
                ldnc4x2(hs_prev + (size_t)tid*4, hs_prev + (size_t)(tid+1024)*4, v0, v1);
                *(float4*)(hs_s + tid*4) = v0;
                *(float4*)(hs_s + (tid+1024)*4) = v1;
            }
            __syncthreads();
            #pragma unroll
            for (int i = 0; i < 8; ++i)
                xv[i] = *(const float4*)(hs_s + (kc + 64*i)*16 + b4*4);

            GATE(3, Whh, 0) GATE(4, Whh, 1) GATE(5, Whh, 2)
            #undef GATE

            if (tid < 256) {   // finalize (hs_s holds h_prev [k][16])
                int b = tid >> 4, c = tid & 15;
                int col = cb*16 + c;
                float gir = vg[0] + bih[col];
                float giz = vg[1] + bih[HH + col];
                float gin = vg[2] + bih[2*HH + col];
                float ghr = vg[3] + bhh[col];
                float ghz = vg[4] + bhh[HH + col];
                float ghn = vg[5] + bhh[2*HH + col];
                float r = 1.f/(1.f + __expf(-(gir + ghr)));
                float z = 1.f/(1.f + __expf(-(giz + ghz)));
                float xn = gin + r*ghn;
                float n = 1.f - 2.f/(__expf(2.f*xn) + 1.f);
                float hprev = hs_s[col*16 + b];
                float hnew = (1.f - z)*n + z*hprev;
                stnc1(hs_new + col*16 + b, hnew);
                stnc1(hbk_new + (size_t)b*HH + col, hnew);
                float hv = (t < olen[b]) ? hnew : 0.f;
                __builtin_nontemporal_store(hv,
                    out + OUT_HID_OFF + ((size_t)t*BB + b)*HH + col);
            }
        }
        ++bno; gridbar(ws, bno);

        // ================= P3: logits + per-block argmax (all 250) =======
        {
            {   // stage h_new [k][b] -> hs_s
                float4 v0, v1;
                ldnc4x2(hs_new + (size_t)tid*4, hs_new + (size_t)(tid+1024)*4, v0, v1);
                *(float4*)(hs_s + tid*4) = v0;
                *(float4*)(hs_s + (tid+1024)*4) = v1;
            }
            __syncthreads();

            int c4 = tid & 3, bq4 = (tid >> 2) & 3, kc = tid >> 4;
            int wv = tid >> 6;
            u64 vmax = 0ull;

            #pragma unroll
            for (int p = 0; p < 4; ++p) {   // 0-2: LDS Wf cols, 3: global cols
                float a00=0,a01=0,a02=0,a03=0, a10=0,a11=0,a12=0,a13=0;
                float a20=0,a21=0,a22=0,a23=0, a30=0,a31=0,a32=0,a33=0;
                #pragma unroll
                for (int i = 0; i < 8; ++i) {   // k = kc + 64*i
                    int k = kc + 64*i;
                    float4 w4;
                    if (p < 3) w4 = *(const float4*)(wf_s + (p*512 + k)*16 + c4*4);
                    else       w4 = *(const float4*)(Wf + (size_t)k*VV + colbase + 48 + c4*4);
                    float4 h4 = *(const float4*)(hs_s + k*16 + bq4*4);
                    a00 += h4.x*w4.x; a01 += h4.x*w4.y; a02 += h4.x*w4.z; a03 += h4.x*w4.w;
                    a10 += h4.y*w4.x; a11 += h4.y*w4.y; a12 += h4.y*w4.z; a13 += h4.y*w4.w;
                    a20 += h4.z*w4.x; a21 += h4.z*w4.y; a22 += h4.z*w4.z; a23 += h4.z*w4.w;
                    a30 += h4.w*w4.x; a31 += h4.w*w4.y; a32 += h4.w*w4.z; a33 += h4.w*w4.w;
                }
                float acc2[4][4] = {{a00,a01,a02,a03},{a10,a11,a12,a13},
                                    {a20,a21,a22,a23},{a30,a31,a32,a33}};
                #pragma unroll
                for (int bi = 0; bi < 4; ++bi)
                    #pragma unroll
                    for (int ci = 0; ci < 4; ++ci) {
                        float vz = acc2[bi][ci];
                        vz += __shfl_xor(vz, 16);
                        vz += __shfl_xor(vz, 32);
                        acc2[bi][ci] = vz;
                    }
                if ((tid & 48) == 0) {
                    #pragma unroll
                    for (int bi = 0; bi < 4; ++bi)
                        *(float4*)(scr + wv*256 + (bq4*4+bi)*16 + c4*4) =
                            make_float4(acc2[bi][0], acc2[bi][1], acc2[bi][2], acc2[bi][3]);
                }
                __syncthreads();
                if (tid < 256) {
                    int b = tid >> 4, c = tid & 15;
                    int col = colbase + p*16 + c;
                    float s = bf[col];
                    #pragma unroll
                    for (int w = 0; w < 16; ++w) s += scr[w*256 + tid];
                    bool active = t < olen[b];
                    __builtin_nontemporal_store(active ? s : 0.f,
                        out + ((size_t)t*BB + b)*VV + col);
                    unsigned u = __float_as_uint(s);
                    u = (u & 0x80000000u) ? ~u : (u | 0x80000000u);
                    u64 e = ((u64)u << 32)
                        | (u64)(0xFFFFFFFFu - (unsigned)col);
                    #pragma unroll
                    for (int off = 1; off < 16; off <<= 1)
                        e = u64max(e, (u64)__shfl_xor((long long)e, off));
                    if ((tid & 15) == 0) vmax = u64max(vmax, e);
                }
                __syncthreads();
            }
            if (tid < 256 && (tid & 15) == 0)
                __hip_atomic_store(&cand[blk*BB + (tid >> 4)], vmax,
                                   __ATOMIC_RELAXED, __HIP_MEMORY_SCOPE_AGENT);
        }
        if (t < TT - 1) { ++bno; gridbar(ws, bno); }
    }
}

extern "C" void kernel_launch(void* const* d_in, const int* in_sizes, int n_in,
                              void* d_out, int out_size, void* d_ws, size_t ws_size,
                              hipStream_t stream) {
    const float* mem = (const float*)d_in[0];
    const float* emb = (const float*)d_in[1];
    const float* Wq  = (const float*)d_in[2];
    const float* bq  = (const float*)d_in[3];
    const float* Wk  = (const float*)d_in[4];
    const float* bk  = (const float*)d_in[5];
    const float* Wv  = (const float*)d_in[6];
    const float* bv  = (const float*)d_in[7];
    const float* Wih = (const float*)d_in[8];
    const float* bih = (const float*)d_in[9];
    const float* Whh = (const float*)d_in[10];
    const float* bhh = (const float*)d_in[11];
    const float* Wf  = (const float*)d_in[12];
    const float* bf  = (const float*)d_in[13];
    const int* olen  = (const int*)d_in[14];
    float* out = (float*)d_out;
    float* ws  = (float*)d_ws;

    hipLaunchKernelGGL(kv_kernel, dim3(2048), dim3(256), 0, stream, mem, Wk, bk, Wv, bv, ws);
    hipLaunchKernelGGL(mega_kernel, dim3(NBLK), dim3(NTHR), 0, stream,
                       emb, Wq, bq, Wih, bih, Whh, bhh, Wf, bf, olen, ws, out);
}

// Round 10
// 2732.580 us; speedup vs baseline: 1.1154x; 1.0066x over previous
//
#include <hip/hip_runtime.h>

#define LL 128      // memory length
#define BB 16       // batch
#define HH 512      // hidden
#define VV 16000    // vocab
#define TT 32       // steps
#define NH 8        // heads
#define DK 64       // head dim
#define NBLK 250    // mega grid (1 block/CU, co-resident)
#define NTHR 1024
#define KVS 528     // padded row stride (floats) for K/V/Wq: breaks L2 set aliasing

// workspace layout (float offsets)
#define WS_K 0                                   // K rows l*BB+b, stride KVS
#define WS_V (2048*KVS)                          // V same
#define WS_WQ (2*2048*KVS)                       // Wq padded copy, 1024 rows stride KVS
#define WS_WFP (WS_WQ + 1024*KVS)                // Wf cols [blk*64+48,+16): [blk][k][16]
#define WS_CTXB (WS_WFP + NBLK*512*16)           // ctx [b][k]          (sc-only)
#define WS_HS0 (WS_CTXB + BB*HH)                 // h [k][b] ping       (sc-only)
#define WS_HS1 (WS_HS0 + BB*HH)
#define WS_HBK0 (WS_HS1 + BB*HH)                 // h [b][k] ping
#define WS_HBK1 (WS_HBK0 + BB*HH)
#define WS_P (WS_HBK1 + BB*HH)                   // p[b][h][128]        (sc-only)
#define WS_CAND (WS_P + BB*NH*LL)                // u64 cand[256][16]   (sc-only)
#define WS_ARR (WS_CAND + 2*256*BB)              // u32 arrive[256]
#define WS_SENSE (WS_ARR + 256)                  // u32

#define OUT_HID_OFF ((size_t)TT*BB*VV)
#define OUT_SC_OFF  (OUT_HID_OFF + (size_t)TT*BB*HH)

typedef float v4f __attribute__((ext_vector_type(4)));
typedef unsigned long long u64;

__device__ __forceinline__ u64 u64max(u64 a, u64 b) { return a > b ? a : b; }

// ---- 16B cache-bypassing (sc0+sc1 -> coherent at LLC) load/store helpers ----
__device__ __forceinline__ float4 ldnc4(const float* p) {
    v4f r;
    asm volatile("global_load_dwordx4 %0, %1, off sc0 sc1\n\t"
                 "s_waitcnt vmcnt(0)"
                 : "=&v"(r) : "v"(p) : "memory");
    return make_float4(r.x, r.y, r.z, r.w);
}
__device__ __forceinline__ void ldnc4x2(const float* p0, const float* p1,
                                        float4& a, float4& b) {
    v4f ra, rb;
    asm volatile("global_load_dwordx4 %0, %2, off sc0 sc1\n\t"
                 "global_load_dwordx4 %1, %3, off sc0 sc1\n\t"
                 "s_waitcnt vmcnt(0)"
                 : "=&v"(ra), "=&v"(rb) : "v"(p0), "v"(p1) : "memory");
    a = make_float4(ra.x, ra.y, ra.z, ra.w);
    b = make_float4(rb.x, rb.y, rb.z, rb.w);
}
__device__ __forceinline__ void ldnc8x4(const u64* p0, const u64* p1,
        const u64* p2, const u64* p3, u64& a, u64& b, u64& c, u64& d) {
    asm volatile("global_load_dwordx2 %0, %4, off sc0 sc1\n\t"
                 "global_load_dwordx2 %1, %5, off sc0 sc1\n\t"
                 "global_load_dwordx2 %2, %6, off sc0 sc1\n\t"
                 "global_load_dwordx2 %3, %7, off sc0 sc1\n\t"
                 "s_waitcnt vmcnt(0)"
                 : "=&v"(a), "=&v"(b), "=&v"(c), "=&v"(d)
                 : "v"(p0), "v"(p1), "v"(p2), "v"(p3) : "memory");
}
__device__ __forceinline__ void ldu32x4(const unsigned* p0, const unsigned* p1,
        const unsigned* p2, const unsigned* p3,
        unsigned& a, unsigned& b, unsigned& c, unsigned& d) {
    asm volatile("global_load_dword %0, %4, off sc0 sc1\n\t"
                 "global_load_dword %1, %5, off sc0 sc1\n\t"
                 "global_load_dword %2, %6, off sc0 sc1\n\t"
                 "global_load_dword %3, %7, off sc0 sc1\n\t"
                 "s_waitcnt vmcnt(0)"
                 : "=&v"(a), "=&v"(b), "=&v"(c), "=&v"(d)
                 : "v"(p0), "v"(p1), "v"(p2), "v"(p3) : "memory");
}
__device__ __forceinline__ void stnc4(float* p, float4 v) {
    v4f r; r.x = v.x; r.y = v.y; r.z = v.z; r.w = v.w;
    asm volatile("global_store_dwordx4 %0, %1, off sc0 sc1"
                 :: "v"(p), "v"(r) : "memory");
}
__device__ __forceinline__ void stnc1(float* p, float v) {
    asm volatile("global_store_dword %0, %1, off sc0 sc1"
                 :: "v"(p), "v"(v) : "memory");
}

// ------ kv projection + Wq/Wf repack + per-call init (grid = 2554 blocks) ----
__global__ __launch_bounds__(256) void kv_kernel(const float* __restrict__ mem,
        const float* __restrict__ Wk, const float* __restrict__ bk,
        const float* __restrict__ Wv, const float* __restrict__ bv,
        const float* __restrict__ Wq, const float* __restrict__ Wf,
        float* __restrict__ ws) {
    int blk = blockIdx.x;
    int tid = threadIdx.x;

    if (blk >= 2048) {
        if (blk < 2304) {          // Wq repack: 4 rows/block, stride KVS
            int r = (blk - 2048)*4 + (tid >> 6);
            int lane = tid & 63;
            float4 v0 = *(const float4*)(Wq + (size_t)r*HH + lane*8);
            float4 v1 = *(const float4*)(Wq + (size_t)r*HH + lane*8 + 4);
            *(float4*)(ws + WS_WQ + (size_t)r*KVS + lane*8) = v0;
            *(float4*)(ws + WS_WQ + (size_t)r*KVS + lane*8 + 4) = v1;
        } else {                   // Wf 16-col slice repack: [mb][k][16]
            int mb = blk - 2304;
            int colb = mb*64 + 48;
            for (int k = tid; k < 512; k += 256) {
                const float* src = Wf + (size_t)k*VV + colb;
                float* dst = ws + WS_WFP + (size_t)mb*8192 + k*16;
                float4 v0 = *(const float4*)(src);
                float4 v1 = *(const float4*)(src + 4);
                float4 v2 = *(const float4*)(src + 8);
                float4 v3 = *(const float4*)(src + 12);
                *(float4*)(dst) = v0;   *(float4*)(dst + 4) = v1;
                *(float4*)(dst + 8) = v2; *(float4*)(dst + 12) = v3;
            }
        }
        return;
    }

    int rg = blk >> 4, ct = blk & 15;
    int isV = ct >= 8;
    int colbase = (ct & 7) * 64;
    const float* W = isV ? Wv : Wk;
    const float* bias = isV ? bv : bk;
    float* outp = ws + (isV ? WS_V : WS_K);
    int rowbase = rg * 16;
    __shared__ float As[16*516];

    {
        const float4* srcp = (const float4*)(mem + (size_t)rowbase*512);
        #pragma unroll
        for (int j = 0; j < 8; ++j) {
            int i = tid + 256*j;
            float4 v = srcp[i];
            int row = i >> 7, c4i = i & 127;
            *(float4*)(As + row*516 + c4i*4) = v;
        }
    }
    if (blk == 0) {   // per-call init (normal stores; kernel-end L2 flush -> LLC)
        for (int i = tid; i < BB*HH; i += 256) {
            ws[WS_HS0 + i] = 0.f;
            ws[WS_HBK0 + i] = 0.f;
        }
        u64* cand = (u64*)(ws + WS_CAND);
        for (int i = tid; i < 256*BB; i += 256) cand[i] = 0ull;
        unsigned* arrive = (unsigned*)(ws + WS_ARR);
        for (int i = tid; i < 256; i += 256)
            arrive[i] = (i == 0 || i >= NBLK) ? 0x7FFFFFFFu : 0u;
        if (tid == 0) *(unsigned*)(ws + WS_SENSE) = 0u;
    }
    __syncthreads();

    int cq = tid & 15;
    int rq4 = (tid >> 4) & 3;
    int kq = tid >> 6;
    float acc[4][4];
    #pragma unroll
    for (int i = 0; i < 4; ++i) { acc[i][0]=0.f; acc[i][1]=0.f; acc[i][2]=0.f; acc[i][3]=0.f; }
    const float* wp = W + colbase + cq*4;
    for (int k4 = kq*32; k4 < kq*32 + 32; ++k4) {
        float4 a0 = *(const float4*)(As + (rq4*4+0)*516 + k4*4);
        float4 a1 = *(const float4*)(As + (rq4*4+1)*516 + k4*4);
        float4 a2 = *(const float4*)(As + (rq4*4+2)*516 + k4*4);
        float4 a3 = *(const float4*)(As + (rq4*4+3)*516 + k4*4);
        const float* wrow = wp + (size_t)(4*k4)*512;
        float4 w0 = *(const float4*)(wrow);
        float4 w1 = *(const float4*)(wrow + 512);
        float4 w2 = *(const float4*)(wrow + 1024);
        float4 w3 = *(const float4*)(wrow + 1536);
        #define KV_FMA(ri, A) \
            acc[ri][0] += A.x*w0.x + A.y*w1.x + A.z*w2.x + A.w*w3.x; \
            acc[ri][1] += A.x*w0.y + A.y*w1.y + A.z*w2.y + A.w*w3.y; \
            acc[ri][2] += A.x*w0.z + A.y*w1.z + A.z*w2.z + A.w*w3.z; \
            acc[ri][3] += A.x*w0.w + A.y*w1.w + A.z*w2.w + A.w*w3.w;
        KV_FMA(0, a0) KV_FMA(1, a1) KV_FMA(2, a2) KV_FMA(3, a3)
        #undef KV_FMA
    }
    __syncthreads();
    float* red = As;
    #pragma unroll
    for (int ri = 0; ri < 4; ++ri)
        *(float4*)(red + ri*1024 + tid*4) =
            make_float4(acc[ri][0], acc[ri][1], acc[ri][2], acc[ri][3]);
    __syncthreads();
    {
        int c4 = tid & 15, row = tid >> 4;
        int rq = row >> 2, ri = row & 3;
        float4 b4v = *(const float4*)(bias + colbase + c4*4);
        float o[4] = {b4v.x, b4v.y, b4v.z, b4v.w};
        #pragma unroll
        for (int kq2 = 0; kq2 < 4; ++kq2) {
            const float* pr = red + ri*1024 + (kq2*64 + rq*16 + c4)*4;
            o[0] += pr[0]; o[1] += pr[1]; o[2] += pr[2]; o[3] += pr[3];
        }
        *(float4*)(outp + (size_t)(rowbase + row)*KVS + colbase + c4*4) =
            make_float4(o[0], o[1], o[2], o[3]);
    }
}

// ---- grid barrier: store-arrive + block-0 wave scan (no RMW contention) ----
__device__ __forceinline__ void gridbar(float* ws, unsigned target) {
    unsigned* arrive = (unsigned*)(ws + WS_ARR);
    unsigned* sense  = (unsigned*)(ws + WS_SENSE);
    asm volatile("s_waitcnt vmcnt(0)" ::: "memory");   // drain this wave's sc stores
    __syncthreads();
    if (blockIdx.x == 0) {
        if (threadIdx.x < 64) {
            const unsigned* ap = arrive + threadIdx.x;
            for (;;) {
                unsigned a0, a1, a2, a3;
                ldu32x4(ap, ap + 64, ap + 128, ap + 192, a0, a1, a2, a3);
                bool ok = (int)(a0 - target) >= 0 && (int)(a1 - target) >= 0 &&
                          (int)(a2 - target) >= 0 && (int)(a3 - target) >= 0;
                if (__all(ok)) break;
                __builtin_amdgcn_s_sleep(2);
            }
            if (threadIdx.x == 0)
                __hip_atomic_store(sense, target, __ATOMIC_RELAXED,
                                   __HIP_MEMORY_SCOPE_AGENT);
        }
    } else if (threadIdx.x == 0) {
        __hip_atomic_store(&arrive[blockIdx.x], target, __ATOMIC_RELAXED,
                           __HIP_MEMORY_SCOPE_AGENT);
        while ((int)(__hip_atomic_load(sense, __ATOMIC_RELAXED,
                     __HIP_MEMORY_SCOPE_AGENT) - target) < 0)
            __builtin_amdgcn_s_sleep(2);
    }
    __syncthreads();
}

// ---------------- mega kernel: all 32 steps ----------------
__global__ __launch_bounds__(NTHR) void mega_kernel(
        const float* __restrict__ emb, const float* __restrict__ bq,
        const float* __restrict__ Wih, const float* __restrict__ bih,
        const float* __restrict__ Whh, const float* __restrict__ bhh,
        const float* __restrict__ Wf,  const float* __restrict__ bf,
        const int* __restrict__ olen, float* __restrict__ ws,
        float* __restrict__ out) {
    __shared__ float wf_s[3*512*16];              // 96 KB: Wf cols [blk*64, +48)
    __shared__ float hs_s[512*16];                // 32 KB: [k][16] staging
    __shared__ __align__(16) float scr[4096];     // 16 KB phase scratch
    int blk = blockIdx.x, tid = threadIdx.x;
    int colbase = blk * 64;
    u64* cand = (u64*)(ws + WS_CAND);
    unsigned bno = 0;

    {   // one-time: stage Wf cols [colbase, colbase+48) into LDS (cached reads)
        #pragma unroll
        for (int j = 0; j < 6; ++j) {
            int i = tid + NTHR*j;                 // 6144 float4
            int p = i >> 11, rem = i & 2047;
            int k = rem >> 2, c4 = rem & 3;
            float4 v = *(const float4*)(Wf + (size_t)k*VV + colbase + p*16 + c4*4);
            *(float4*)(wf_s + (p*512 + k)*16 + c4*4) = v;
        }
    }

    for (int t = 0; t < TT; ++t) {
        const float* hs_prev  = ws + ((t & 1) ? WS_HS1  : WS_HS0);
        float*       hs_new   = ws + ((t & 1) ? WS_HS0  : WS_HS1);
        const float* hbk_prev = ws + ((t & 1) ? WS_HBK1 : WS_HBK0);
        float*       hbk_new  = ws + ((t & 1) ? WS_HBK0 : WS_HBK1);

        // ================= P1: attention (blocks 0..127) =================
        if (blk < 128) {
            int b = blk >> 3, h = blk & 7;
            float* q    = scr;                    // 1024
            float* buf  = scr + 1024;             // 1024 (part / sp / cpart)
            float* qh   = scr + 2048;             // 64
            float* pbuf = scr + 2112;             // 128
            float* ctxv = scr + 2240;             // 64

            if (t > 0) {   // resolve argmax from 256 (padded) block candidates
                if (tid < 64) {
                    const u64* cp = cand + b;
                    u64 a0, a1, a2, a3;
                    ldnc8x4(cp + (size_t)tid*BB, cp + (size_t)(tid+64)*BB,
                            cp + (size_t)(tid+128)*BB, cp + (size_t)(tid+192)*BB,
                            a0, a1, a2, a3);
                    u64 m = u64max(u64max(a0, a1), u64max(a2, a3));
                    #pragma unroll
                    for (int off = 32; off; off >>= 1)
                        m = u64max(m, (u64)__shfl_xor((long long)m, off));
                    if (tid == 0)
                        *(unsigned*)(scr + 2304) = 0xFFFFFFFFu - (unsigned)(m & 0xFFFFFFFFull);
                }
                __syncthreads();
            }
            unsigned idx = (t > 0) ? *(unsigned*)(scr + 2304) : 0u;
            if (tid < 128) {
                *(float4*)(q + tid*4) = ((const float4*)emb)[(size_t)idx*128 + tid];
            } else if (tid < 256) {
                int j = tid - 128;
                *(float4*)(q + 512 + j*4) = ldnc4(hbk_prev + (size_t)b*HH + j*4);
            }
            __syncthreads();

            {   // qproj (padded Wq): c4 = tid&15 (4 cols), kc = tid>>4, k = kc+64i
                int c4 = tid & 15, kc = tid >> 4;
                const float* wp = ws + WS_WQ + (size_t)kc*KVS + h*64 + c4*4;
                float ax=0.f, ay=0.f, az=0.f, aw=0.f;
                #pragma unroll
                for (int i = 0; i < 16; ++i) {
                    float x = q[kc + 64*i];
                    float4 w4 = *(const float4*)wp;
                    wp += (size_t)64*KVS;
                    ax += x*w4.x; ay += x*w4.y; az += x*w4.z; aw += x*w4.w;
                }
                float v;
                v = ax; v += __shfl_xor(v,16); v += __shfl_xor(v,32); ax = v;
                v = ay; v += __shfl_xor(v,16); v += __shfl_xor(v,32); ay = v;
                v = az; v += __shfl_xor(v,16); v += __shfl_xor(v,32); az = v;
                v = aw; v += __shfl_xor(v,16); v += __shfl_xor(v,32); aw = v;
                int wv = tid >> 6;
                if ((tid & 48) == 0)
                    *(float4*)(buf + wv*64 + c4*4) = make_float4(ax, ay, az, aw);
            }
            __syncthreads();
            if (tid < 64) {
                float s = bq[h*64 + tid];
                #pragma unroll
                for (int wv = 0; wv < 16; ++wv) s += buf[wv*64 + tid];
                qh[tid] = s;
            }
            __syncthreads();

            {   // scores (padded K): l = tid&127, jh = tid>>7
                int l = tid & 127, jh = tid >> 7;
                const float4* kr = (const float4*)(ws + WS_K +
                                   (size_t)(l*BB + b)*KVS + h*DK) + jh*2;
                const float4* q4 = (const float4*)qh + jh*2;
                float4 k0 = kr[0], k1 = kr[1], q0 = q4[0], q1 = q4[1];
                buf[jh*128 + l] = q0.x*k0.x + q0.y*k0.y + q0.z*k0.z + q0.w*k0.w
                                + q1.x*k1.x + q1.y*k1.y + q1.z*k1.z + q1.w*k1.w;
            }
            __syncthreads();

            if (tid < 64) {   // softmax over 128 (wave 0)
                float s0v = 0.f, s1v = 0.f;
                #pragma unroll
                for (int jh = 0; jh < 8; ++jh) {
                    s0v += buf[jh*128 + tid];
                    s1v += buf[jh*128 + 64 + tid];
                }
                s0v *= 0.125f; s1v *= 0.125f;
                float m = fmaxf(s0v, s1v);
                #pragma unroll
                for (int off = 32; off; off >>= 1) m = fmaxf(m, __shfl_xor(m, off));
                float e0 = __expf(s0v - m), e1 = __expf(s1v - m);
                float sum = e0 + e1;
                #pragma unroll
                for (int off = 32; off; off >>= 1) sum += __shfl_xor(sum, off);
                float inv = 1.f / sum;
                pbuf[tid]      = e0 * inv;
                pbuf[64 + tid] = e1 * inv;
            }
            __syncthreads();
            if (tid < 32)
                stnc4(ws + WS_P + (size_t)(b*NH + h)*LL + tid*4,
                      *(float4*)(pbuf + tid*4));

            {   // ctx (padded V): c = tid&63, lc = tid>>6 (16 slices of 8 l)
                int c = tid & 63, lc = tid >> 6;
                const float* Vp = ws + WS_V + h*DK + c;
                float a = 0.f;
                #pragma unroll
                for (int li = 0; li < 8; ++li) {
                    int l = lc*8 + li;
                    a += pbuf[l] * Vp[(size_t)(l*BB + b)*KVS];
                }
                buf[lc*64 + c] = a;
            }
            __syncthreads();
            if (tid < 64) {
                float v = 0.f;
                #pragma unroll
                for (int lc = 0; lc < 16; ++lc) v += buf[lc*64 + tid];
                ctxv[tid] = v;
            }
            __syncthreads();
            if (tid < 16)
                stnc4(ws + WS_CTXB + (size_t)b*HH + h*64 + tid*4,
                      *(float4*)(ctxv + tid*4));
        }
        ++bno; gridbar(ws, bno);

        // ================= P2: GRU gates + finalize (blocks 0..31) =======
        if (blk < 32) {
            int cb = blk;
            int bb = cb >> 1, l0 = (cb & 1) * 64;

            if (tid < 128) {   // P slices for sc output -> scr[2048..2559]
                int hq = tid >> 4, li = (tid & 15) * 4;
                float4 pv = ldnc4(ws + WS_P + (size_t)(bb*NH + hq)*LL + l0 + li);
                *(float4*)(scr + 2048 + hq*64 + li) = pv;
            }
            {   // ctx [b][k] -> hs_s [k][16]
                int b = tid & 15, kq = tid >> 4;     // k = kq*8 .. +7
                float4 v0, v1;
                ldnc4x2(ws + WS_CTXB + (size_t)b*HH + kq*8,
                        ws + WS_CTXB + (size_t)b*HH + kq*8 + 4, v0, v1);
                hs_s[(kq*8+0)*16 + b] = v0.x; hs_s[(kq*8+1)*16 + b] = v0.y;
                hs_s[(kq*8+2)*16 + b] = v0.z; hs_s[(kq*8+3)*16 + b] = v0.w;
                hs_s[(kq*8+4)*16 + b] = v1.x; hs_s[(kq*8+5)*16 + b] = v1.y;
                hs_s[(kq*8+6)*16 + b] = v1.z; hs_s[(kq*8+7)*16 + b] = v1.w;
            }
            __syncthreads();
            if (tid < 64) {   // sc output
                float s = 0.f;
                #pragma unroll
                for (int hq = 0; hq < NH; ++hq) s += scr[2048 + hq*64 + tid];
                float v = (t < olen[bb]) ? s*0.125f : 0.f;
                __builtin_nontemporal_store(v,
                    out + OUT_SC_OFF + ((size_t)t*BB + bb)*LL + l0 + tid);
            }
            __syncthreads();

            int c4 = tid & 3, b4 = (tid >> 2) & 3, kc = tid >> 4;
            int wv = tid >> 6;
            float4 xv[8];
            #pragma unroll
            for (int i = 0; i < 8; ++i)
                xv[i] = *(const float4*)(hs_s + (kc + 64*i)*16 + b4*4);
            float vg[6];

            #define GATE(gslot, WMAT, GG) { \
                const float* wp = WMAT + (size_t)kc*(3*HH) + (GG)*HH + cb*16 + c4*4; \
                float a00=0,a01=0,a02=0,a03=0, a10=0,a11=0,a12=0,a13=0; \
                float a20=0,a21=0,a22=0,a23=0, a30=0,a31=0,a32=0,a33=0; \
                _Pragma("unroll") \
                for (int i = 0; i < 8; ++i) { \
                    float4 w4 = *(const float4*)wp; wp += (size_t)64*(3*HH); \
                    float4 x4 = xv[i]; \
                    a00 += x4.x*w4.x; a01 += x4.x*w4.y; a02 += x4.x*w4.z; a03 += x4.x*w4.w; \
                    a10 += x4.y*w4.x; a11 += x4.y*w4.y; a12 += x4.y*w4.z; a13 += x4.y*w4.w; \
                    a20 += x4.z*w4.x; a21 += x4.z*w4.y; a22 += x4.z*w4.z; a23 += x4.z*w4.w; \
                    a30 += x4.w*w4.x; a31 += x4.w*w4.y; a32 += x4.w*w4.z; a33 += x4.w*w4.w; \
                } \
                float acc2[4][4] = {{a00,a01,a02,a03},{a10,a11,a12,a13}, \
                                    {a20,a21,a22,a23},{a30,a31,a32,a33}}; \
                _Pragma("unroll") \
                for (int bi = 0; bi < 4; ++bi) \
                    _Pragma("unroll") \
                    for (int ci = 0; ci < 4; ++ci) { \
                        float vz = acc2[bi][ci]; \
                        vz += __shfl_xor(vz, 16); \
                        vz += __shfl_xor(vz, 32); \
                        acc2[bi][ci] = vz; \
                    } \
                if ((tid & 48) == 0) { \
                    _Pragma("unroll") \
                    for (int bi = 0; bi < 4; ++bi) \
                        *(float4*)(scr + wv*256 + (b4*4+bi)*16 + c4*4) = \
                            make_float4(acc2[bi][0], acc2[bi][1], acc2[bi][2], acc2[bi][3]); \
                } \
                __syncthreads(); \
                float sred = 0.f; \
                if (tid < 256) { \
                    _Pragma("unroll") \
                    for (int w = 0; w < 16; ++w) sred += scr[w*256 + tid]; \
                } \
                vg[gslot] = sred; \
                __syncthreads(); }

            GATE(0, Wih, 0) GATE(1, Wih, 1) GATE(2, Wih, 2)

            {   // restage hs_s with h_prev [k][b] (direct copy)
                float4 v0, v1;
                ldnc4x2(hs_prev + (size_t)tid*4, hs_prev + (size_t)(tid+1024)*4, v0, v1);
                *(float4*)(hs_s + tid*4) = v0;
                *(float4*)(hs_s + (tid+1024)*4) = v1;
            }
            __syncthreads();
            #pragma unroll
            for (int i = 0; i < 8; ++i)
                xv[i] = *(const float4*)(hs_s + (kc + 64*i)*16 + b4*4);

            GATE(3, Whh, 0) GATE(4, Whh, 1) GATE(5, Whh, 2)
            #undef GATE

            if (tid < 256) {   // finalize (hs_s holds h_prev [k][16])
                int b = tid >> 4, c = tid & 15;
                int col = cb*16 + c;
                float gir = vg[0] + bih[col];
                float giz = vg[1] + bih[HH + col];
                float gin = vg[2] + bih[2*HH + col];
                float ghr = vg[3] + bhh[col];
                float ghz = vg[4] + bhh[HH + col];
                float ghn = vg[5] + bhh[2*HH + col];
                float r = 1.f/(1.f + __expf(-(gir + ghr)));
                float z = 1.f/(1.f + __expf(-(giz + ghz)));
                float xn = gin + r*ghn;
                float n = 1.f - 2.f/(__expf(2.f*xn) + 1.f);
                float hprev = hs_s[col*16 + b];
                float hnew = (1.f - z)*n + z*hprev;
                stnc1(hs_new + col*16 + b, hnew);
                stnc1(hbk_new + (size_t)b*HH + col, hnew);
                float hv = (t < olen[b]) ? hnew : 0.f;
                __builtin_nontemporal_store(hv,
                    out + OUT_HID_OFF + ((size_t)t*BB + b)*HH + col);
            }
        }
        ++bno; gridbar(ws, bno);

        // ================= P3: logits + per-block argmax (all 250) =======
        {
            {   // stage h_new [k][b] -> hs_s
                float4 v0, v1;
                ldnc4x2(hs_new + (size_t)tid*4, hs_new + (size_t)(tid+1024)*4, v0, v1);
                *(float4*)(hs_s + tid*4) = v0;
                *(float4*)(hs_s + (tid+1024)*4) = v1;
            }
            __syncthreads();

            int c4 = tid & 3, bq4 = (tid >> 2) & 3, kc = tid >> 4;
            int wv = tid >> 6;
            u64 vmax = 0ull;

            #pragma unroll
            for (int p = 0; p < 4; ++p) {   // 0-2: LDS Wf cols, 3: ws repacked cols
                float a00=0,a01=0,a02=0,a03=0, a10=0,a11=0,a12=0,a13=0;
                float a20=0,a21=0,a22=0,a23=0, a30=0,a31=0,a32=0,a33=0;
                #pragma unroll
                for (int i = 0; i < 8; ++i) {   // k = kc + 64*i
                    int k = kc + 64*i;
                    float4 w4;
                    if (p < 3) w4 = *(const float4*)(wf_s + (p*512 + k)*16 + c4*4);
                    else       w4 = *(const float4*)(ws + WS_WFP + (size_t)blk*8192 + k*16 + c4*4);
                    float4 h4 = *(const float4*)(hs_s + k*16 + bq4*4);
                    a00 += h4.x*w4.x; a01 += h4.x*w4.y; a02 += h4.x*w4.z; a03 += h4.x*w4.w;
                    a10 += h4.y*w4.x; a11 += h4.y*w4.y; a12 += h4.y*w4.z; a13 += h4.y*w4.w;
                    a20 += h4.z*w4.x; a21 += h4.z*w4.y; a22 += h4.z*w4.z; a23 += h4.z*w4.w;
                    a30 += h4.w*w4.x; a31 += h4.w*w4.y; a32 += h4.w*w4.z; a33 += h4.w*w4.w;
                }
                float acc2[4][4] = {{a00,a01,a02,a03},{a10,a11,a12,a13},
                                    {a20,a21,a22,a23},{a30,a31,a32,a33}};
                #pragma unroll
                for (int bi = 0; bi < 4; ++bi)
                    #pragma unroll
                    for (int ci = 0; ci < 4; ++ci) {
                        float vz = acc2[bi][ci];
                        vz += __shfl_xor(vz, 16);
                        vz += __shfl_xor(vz, 32);
                        acc2[bi][ci] = vz;
                    }
                if ((tid & 48) == 0) {
                    #pragma unroll
                    for (int bi = 0; bi < 4; ++bi)
                        *(float4*)(scr + wv*256 + (bq4*4+bi)*16 + c4*4) =
                            make_float4(acc2[bi][0], acc2[bi][1], acc2[bi][2], acc2[bi][3]);
                }
                __syncthreads();
                if (tid < 256) {
                    int b = tid >> 4, c = tid & 15;
                    int col = colbase + p*16 + c;
                    float s = bf[col];
                    #pragma unroll
                    for (int w = 0; w < 16; ++w) s += scr[w*256 + tid];
                    bool active = t < olen[b];
                    __builtin_nontemporal_store(active ? s : 0.f,
                        out + ((size_t)t*BB + b)*VV + col);
                    unsigned u = __float_as_uint(s);
                    u = (u & 0x80000000u) ? ~u : (u | 0x80000000u);
                    u64 e = ((u64)u << 32)
                        | (u64)(0xFFFFFFFFu - (unsigned)col);
                    #pragma unroll
                    for (int off = 1; off < 16; off <<= 1)
                        e = u64max(e, (u64)__shfl_xor((long long)e, off));
                    if ((tid & 15) == 0) vmax = u64max(vmax, e);
                }
                __syncthreads();
            }
            if (tid < 256 && (tid & 15) == 0)
                __hip_atomic_store(&cand[blk*BB + (tid >> 4)], vmax,
                                   __ATOMIC_RELAXED, __HIP_MEMORY_SCOPE_AGENT);
        }
        if (t < TT - 1) { ++bno; gridbar(ws, bno); }
    }
}

extern "C" void kernel_launch(void* const* d_in, const int* in_sizes, int n_in,
                              void* d_out, int out_size, void* d_ws, size_t ws_size,
                              hipStream_t stream) {
    const float* mem = (const float*)d_in[0];
    const float* emb = (const float*)d_in[1];
    const float* Wq  = (const float*)d_in[2];
    const float* bq  = (const float*)d_in[3];
    const float* Wk  = (const float*)d_in[4];
    const float* bk  = (const float*)d_in[5];
    const float* Wv  = (const float*)d_in[6];
    const float* bv  = (const float*)d_in[7];
    const float* Wih = (const float*)d_in[8];
    const float* bih = (const float*)d_in[9];
    const float* Whh = (const float*)d_in[10];
    const float* bhh = (const float*)d_in[11];
    const float* Wf  = (const float*)d_in[12];
    const float* bf  = (const float*)d_in[13];
    const int* olen  = (const int*)d_in[14];
    float* out = (float*)d_out;
    float* ws  = (float*)d_ws;

    hipLaunchKernelGGL(kv_kernel, dim3(2554), dim3(256), 0, stream,
                       mem, Wk, bk, Wv, bv, Wq, Wf, ws);
    hipLaunchKernelGGL(mega_kernel, dim3(NBLK), dim3(NTHR), 0, stream,
                       emb, bq, Wih, bih, Whh, bhh, Wf, bf, olen, ws, out);
}